// Round 1
// baseline (3700.098 us; speedup 1.0000x reference)
//
#include <hip/hip_runtime.h>
#include <math.h>

// Problem constants
#define BB   4
#define LL   4096
#define DIMC 2048
#define SC   128
#define MM   (BB*LL)        // 16384 rows
#define NC   64             // scan chunks per sequence
#define LCH  (LL/NC)        // 64 = chunk length

// ---------------------------------------------------------------------------
// Kernel 0: transpose dt_w (S,2*DIM) -> (2*DIM,S) and pg_w (S,DIM) -> (DIM,S)
// ---------------------------------------------------------------------------
__global__ void transpose_w(const float* __restrict__ dt_w,
                            const float* __restrict__ pg_w,
                            float* __restrict__ dtw_t,
                            float* __restrict__ pgw_t) {
    int i = threadIdx.x + blockIdx.x * 256;
    if (i < 2*DIMC*SC) {                 // 4096*128
        int d = i >> 7, s = i & 127;
        dtw_t[i] = dt_w[(size_t)s * (2*DIMC) + d];
    }
    int j = i - 2*DIMC*SC;
    if (j >= 0 && j < DIMC*SC) {         // 2048*128
        int d = j >> 7, s = j & 127;
        pgw_t[j] = pg_w[(size_t)s * DIMC + d];
    }
}

// ---------------------------------------------------------------------------
// Kernel 1: fused projections. Block = 128 threads (one per s), 32 rows/block.
// Produces A (complex) and Bx (complex) in (m, s) interleaved layout.
// ---------------------------------------------------------------------------
__global__ __launch_bounds__(128, 3) void phase1(
    const float* __restrict__ x,        // (M, DIM, 2)
    const float* __restrict__ dtw_t,    // (4096, 128)
    const float* __restrict__ pgw_t,    // (2048, 128)
    const float* __restrict__ Br,       // (2048, 128)
    const float* __restrict__ Bi,       // (2048, 128)
    const float* __restrict__ log_A_real,
    const float* __restrict__ log_A_imag,
    const float* __restrict__ dt_b,
    const float* __restrict__ dt_bias,
    const float* __restrict__ pg_b,
    float* __restrict__ Abuf,
    float* __restrict__ Bxbuf)
{
    const int s  = threadIdx.x;          // 0..127
    const int m0 = blockIdx.x * 32;

    __shared__ __align__(16) float2 xs[32][64];   // 16 KB  (xr, xi)
    __shared__ __align__(16) float  cs[32][64];   // 8 KB   |x|

    float accd[32], accp[32], accbr[32], accbi[32];
    #pragma unroll
    for (int r = 0; r < 32; ++r) { accd[r]=0.f; accp[r]=0.f; accbr[r]=0.f; accbi[r]=0.f; }

    const float2* x2 = (const float2*)x;

    for (int kt = 0; kt < DIMC; kt += 64) {
        __syncthreads();
        #pragma unroll
        for (int j = 0; j < 16; ++j) {
            int i  = threadIdx.x + j * 128;
            int r  = i >> 6, kk = i & 63;
            float2 xv = x2[(size_t)(m0 + r) * DIMC + kt + kk];
            xs[r][kk] = xv;
            cs[r][kk] = sqrtf(fmaf(xv.x, xv.x, xv.y * xv.y));
        }
        __syncthreads();

        const float* wdr_p = dtw_t + (size_t)kt * SC + s;
        const float* wdi_p = dtw_t + (size_t)(DIMC + kt) * SC + s;
        const float* wbr_p = Br    + (size_t)kt * SC + s;
        const float* wbi_p = Bi    + (size_t)kt * SC + s;
        const float* wpg_p = pgw_t + (size_t)kt * SC + s;

        for (int kk = 0; kk < 64; kk += 2) {
            float w0dr = wdr_p[(size_t)kk*SC],     w1dr = wdr_p[(size_t)(kk+1)*SC];
            float w0di = wdi_p[(size_t)kk*SC],     w1di = wdi_p[(size_t)(kk+1)*SC];
            float w0br = wbr_p[(size_t)kk*SC],     w1br = wbr_p[(size_t)(kk+1)*SC];
            float w0bi = wbi_p[(size_t)kk*SC],     w1bi = wbi_p[(size_t)(kk+1)*SC];
            float w0pg = wpg_p[(size_t)kk*SC],     w1pg = wpg_p[(size_t)(kk+1)*SC];
            #pragma unroll
            for (int r = 0; r < 32; ++r) {
                float4 xv = *(const float4*)&xs[r][kk];   // (xr0,xi0,xr1,xi1)
                float2 cb = *(const float2*)&cs[r][kk];
                accd[r]  = fmaf(xv.x,  w0dr, accd[r]);
                accd[r]  = fmaf(xv.y,  w0di, accd[r]);
                accbr[r] = fmaf(xv.x,  w0br, accbr[r]);
                accbr[r] = fmaf(-xv.y, w0bi, accbr[r]);
                accbi[r] = fmaf(xv.x,  w0bi, accbi[r]);
                accbi[r] = fmaf(xv.y,  w0br, accbi[r]);
                accp[r]  = fmaf(cb.x,  w0pg, accp[r]);
                accd[r]  = fmaf(xv.z,  w1dr, accd[r]);
                accd[r]  = fmaf(xv.w,  w1di, accd[r]);
                accbr[r] = fmaf(xv.z,  w1br, accbr[r]);
                accbr[r] = fmaf(-xv.w, w1bi, accbr[r]);
                accbi[r] = fmaf(xv.z,  w1bi, accbi[r]);
                accbi[r] = fmaf(xv.w,  w1br, accbi[r]);
                accp[r]  = fmaf(cb.y,  w1pg, accp[r]);
            }
        }
    }

    // epilogue: dt=softplus, A = p + (1-p)*exp(-dt*eA)*eig, Bx = (1-p)*dt*Bx0
    float eAr   = expf(log_A_real[s]);
    float eig_r = cosf(log_A_imag[s]);
    float eig_i = sinf(log_A_imag[s]);
    float bsum  = dt_b[s] + dt_bias[s];
    float pgb   = pg_b[s];
    float2* A2  = (float2*)Abuf;
    float2* Bx2 = (float2*)Bxbuf;
    #pragma unroll 4
    for (int r = 0; r < 32; ++r) {
        float z    = accd[r] + bsum;
        float dt   = fmaxf(z, 0.f) + log1pf(expf(-fabsf(z)));   // softplus
        float amag = expf(-dt * eAr);
        float zp   = accp[r] + pgb;
        float pr   = 1.f / (1.f + expf(-zp));
        float omp  = 1.f - pr;
        float Ar_  = fmaf(omp, amag * eig_r, pr);
        float Ai_  = omp * amag * eig_i;
        float sc   = omp * dt;
        size_t base = (size_t)(m0 + r) * SC + s;
        A2[base]  = make_float2(Ar_, Ai_);
        Bx2[base] = make_float2(sc * accbr[r], sc * accbi[r]);
    }
}

// ---------------------------------------------------------------------------
// Kernel 2a: per-chunk reduce of (A,B) pairs. Grid = B*NC, block = 128 (s).
// ---------------------------------------------------------------------------
__global__ void scan_reduce(const float* __restrict__ Abuf,
                            const float* __restrict__ Bxbuf,
                            float* __restrict__ aggA,
                            float* __restrict__ aggB) {
    int s = threadIdx.x;
    int c = blockIdx.x & (NC-1);
    int b = blockIdx.x >> 6;
    const float2* A2  = (const float2*)Abuf;
    const float2* Bx2 = (const float2*)Bxbuf;
    size_t base = ((size_t)(b * LL + c * LCH) * SC + s);
    float2 a0 = A2[base], b0 = Bx2[base];
    float ar = a0.x, ai = a0.y, br = b0.x, bi = b0.y;
    #pragma unroll 4
    for (int l = 1; l < LCH; ++l) {
        float2 al = A2[base + (size_t)l * SC];
        float2 bl = Bx2[base + (size_t)l * SC];
        float nar = ar*al.x - ai*al.y;
        float nai = ar*al.y + ai*al.x;
        float nbr = br*al.x - bi*al.y + bl.x;
        float nbi = br*al.y + bi*al.x + bl.y;
        ar = nar; ai = nai; br = nbr; bi = nbi;
    }
    ((float2*)aggA)[(size_t)blockIdx.x * SC + s] = make_float2(ar, ai);
    ((float2*)aggB)[(size_t)blockIdx.x * SC + s] = make_float2(br, bi);
}

// ---------------------------------------------------------------------------
// Kernel 2b: exclusive scan of chunk aggregates (spine). 512 threads total.
// Only the B-component of the prefix is needed (h_init = 0).
// ---------------------------------------------------------------------------
__global__ void scan_spine(const float* __restrict__ aggA,
                           const float* __restrict__ aggB,
                           float* __restrict__ preB) {
    int t = threadIdx.x + blockIdx.x * blockDim.x;   // 0..511
    int s = t & 127, b = t >> 7;
    const float2* A2 = (const float2*)aggA;
    const float2* B2 = (const float2*)aggB;
    float2* P2 = (float2*)preB;
    float pa_r = 1.f, pa_i = 0.f, pb_r = 0.f, pb_i = 0.f;
    for (int c = 0; c < NC; ++c) {
        size_t idx = (size_t)(b * NC + c) * SC + s;
        P2[idx] = make_float2(pb_r, pb_i);
        float2 a = A2[idx], bb = B2[idx];
        float nar = pa_r*a.x - pa_i*a.y;
        float nai = pa_r*a.y + pa_i*a.x;
        float nbr = pb_r*a.x - pb_i*a.y + bb.x;
        float nbi = pb_r*a.y + pb_i*a.x + bb.y;
        pa_r = nar; pa_i = nai; pb_r = nbr; pb_i = nbi;
    }
}

// ---------------------------------------------------------------------------
// Kernel 2c: apply prefixes, write h (and h_last output). Grid = B*NC.
// ---------------------------------------------------------------------------
__global__ void scan_apply(const float* __restrict__ Abuf,
                           const float* __restrict__ Bxbuf,
                           const float* __restrict__ preB,
                           float* __restrict__ hbuf,
                           float* __restrict__ d_out) {
    int s = threadIdx.x;
    int c = blockIdx.x & (NC-1);
    int b = blockIdx.x >> 6;
    const float2* A2  = (const float2*)Abuf;
    const float2* Bx2 = (const float2*)Bxbuf;
    float2 hp = ((const float2*)preB)[(size_t)blockIdx.x * SC + s];
    float hr = hp.x, hi = hp.y;
    size_t base = ((size_t)(b * LL + c * LCH) * SC + s);
    float2* h2 = (float2*)hbuf;
    #pragma unroll 4
    for (int l = 0; l < LCH; ++l) {
        float2 al = A2[base + (size_t)l * SC];
        float2 bl = Bx2[base + (size_t)l * SC];
        float nr = al.x*hr - al.y*hi + bl.x;
        float ni = al.x*hi + al.y*hr + bl.y;
        hr = nr; hi = ni;
        h2[base + (size_t)l * SC] = make_float2(hr, hi);
    }
    if (c == NC - 1) {   // l = L-1 -> h_last
        float2* hl = (float2*)(d_out + (size_t)MM * DIMC * 2);
        hl[b * SC + s] = make_float2(hr, hi);
    }
}

// ---------------------------------------------------------------------------
// Kernel 3: y = h @ (Cr + i Ci) + D*x. Block = 256 (d), 32 rows/block.
// ---------------------------------------------------------------------------
__global__ __launch_bounds__(256, 4) void phase3(
    const float* __restrict__ hbuf,
    const float* __restrict__ Cr,      // (S, DIM)
    const float* __restrict__ Ci,      // (S, DIM)
    const float* __restrict__ x,       // (M, DIM, 2)
    const float* __restrict__ Dw,      // (DIM, 2)
    float* __restrict__ out)
{
    const int tid = threadIdx.x;
    const int m0  = blockIdx.x * 32;
    __shared__ __align__(16) float2 hs[32][128];   // 32 KB
    const float2* h2 = (const float2*)hbuf;
    #pragma unroll
    for (int j = 0; j < 16; ++j) {
        int i = tid + j * 256;
        hs[i >> 7][i & 127] = h2[(size_t)(m0 + (i >> 7)) * SC + (i & 127)];
    }
    __syncthreads();

    const float2* x2 = (const float2*)x;
    float2* o2 = (float2*)out;

    for (int d0 = 0; d0 < DIMC; d0 += 256) {
        int d = d0 + tid;
        float yr[32], yi[32];
        #pragma unroll
        for (int r = 0; r < 32; ++r) { yr[r] = 0.f; yi[r] = 0.f; }
        for (int s = 0; s < SC; ++s) {
            float cr = Cr[(size_t)s * DIMC + d];
            float ci = Ci[(size_t)s * DIMC + d];
            #pragma unroll
            for (int r = 0; r < 32; ++r) {
                float2 h = hs[r][s];
                yr[r] = fmaf(h.x,  cr, yr[r]);
                yr[r] = fmaf(-h.y, ci, yr[r]);
                yi[r] = fmaf(h.x,  ci, yi[r]);
                yi[r] = fmaf(h.y,  cr, yi[r]);
            }
        }
        float dre = Dw[d*2], dim_ = Dw[d*2 + 1];
        #pragma unroll 4
        for (int r = 0; r < 32; ++r) {
            size_t m = (size_t)(m0 + r);
            float2 xv = x2[m * DIMC + d];
            float orr = yr[r] + dre * xv.x - dim_ * xv.y;
            float oii = yi[r] + dre * xv.y + dim_ * xv.x;
            o2[m * DIMC + d] = make_float2(orr, oii);
        }
    }
}

// ---------------------------------------------------------------------------
extern "C" void kernel_launch(void* const* d_in, const int* in_sizes, int n_in,
                              void* d_out, int out_size, void* d_ws, size_t ws_size,
                              hipStream_t stream) {
    const float* x          = (const float*)d_in[0];
    const float* log_A_real = (const float*)d_in[1];
    const float* log_A_imag = (const float*)d_in[2];
    const float* Dw         = (const float*)d_in[3];
    const float* dt_w       = (const float*)d_in[4];
    const float* dt_b       = (const float*)d_in[5];
    const float* dt_bias    = (const float*)d_in[6];
    const float* Br         = (const float*)d_in[7];
    const float* Bi         = (const float*)d_in[8];
    const float* Cr         = (const float*)d_in[9];
    const float* Ci         = (const float*)d_in[10];
    const float* pg_w       = (const float*)d_in[11];
    const float* pg_b       = (const float*)d_in[12];

    float* out = (float*)d_out;
    float* ws  = (float*)d_ws;

    float* dtw_t = ws;                        // 524288
    float* pgw_t = dtw_t + 2*DIMC*SC;         // 262144
    float* Abuf  = pgw_t + DIMC*SC;           // 4194304 (M*S complex)
    float* Bxbuf = Abuf  + (size_t)MM*SC*2;   // 4194304
    float* hbuf  = Bxbuf + (size_t)MM*SC*2;   // 4194304
    float* aggA  = hbuf  + (size_t)MM*SC*2;   // 65536
    float* aggB  = aggA  + BB*NC*SC*2;        // 65536
    float* preB  = aggB  + BB*NC*SC*2;        // 65536
    // total ws use: 13,565,952 floats = 54.3 MB

    hipLaunchKernelGGL(transpose_w, dim3(3072), dim3(256), 0, stream,
                       dt_w, pg_w, dtw_t, pgw_t);
    hipLaunchKernelGGL(phase1, dim3(MM/32), dim3(128), 0, stream,
                       x, dtw_t, pgw_t, Br, Bi, log_A_real, log_A_imag,
                       dt_b, dt_bias, pg_b, Abuf, Bxbuf);
    hipLaunchKernelGGL(scan_reduce, dim3(BB*NC), dim3(128), 0, stream,
                       Abuf, Bxbuf, aggA, aggB);
    hipLaunchKernelGGL(scan_spine, dim3(2), dim3(256), 0, stream,
                       aggA, aggB, preB);
    hipLaunchKernelGGL(scan_apply, dim3(BB*NC), dim3(128), 0, stream,
                       Abuf, Bxbuf, preB, hbuf, out);
    hipLaunchKernelGGL(phase3, dim3(MM/32), dim3(256), 0, stream,
                       hbuf, Cr, Ci, x, Dw, out);
}

// Round 2
// 2504.658 us; speedup vs baseline: 1.4773x; 1.4773x over previous
//
#include <hip/hip_runtime.h>
#include <math.h>

// Problem constants
#define BB   4
#define LL   4096
#define DIMC 2048
#define SC   128
#define MM   (BB*LL)        // 16384 rows
#define NC   64             // scan chunks per sequence
#define LCH  (LL/NC)        // 64 = chunk length

// ---------------------------------------------------------------------------
// Kernel 0: transpose dt_w (S,2*DIM) -> (2*DIM,S) and pg_w (S,DIM) -> (DIM,S)
// ---------------------------------------------------------------------------
__global__ void transpose_w(const float* __restrict__ dt_w,
                            const float* __restrict__ pg_w,
                            float* __restrict__ dtw_t,
                            float* __restrict__ pgw_t) {
    int i = threadIdx.x + blockIdx.x * 256;
    if (i < 2*DIMC*SC) {                 // 4096*128
        int d = i >> 7, s = i & 127;
        dtw_t[i] = dt_w[(size_t)s * (2*DIMC) + d];
    }
    int j = i - 2*DIMC*SC;
    if (j >= 0 && j < DIMC*SC) {         // 2048*128
        int d = j >> 7, s = j & 127;
        pgw_t[j] = pg_w[(size_t)s * DIMC + d];
    }
}

// ---------------------------------------------------------------------------
// Kernel 1: fused projections. Block = 256 threads: (s:128) x (row-half:2).
// 32 rows/block, 16 rows/thread -> 64 fp32 accumulators/thread (NO SPILL;
// round-1 had 128 accs under a ~170-VGPR cap -> 530 MB of scratch traffic).
// ---------------------------------------------------------------------------
__global__ __launch_bounds__(256, 2) void phase1(
    const float* __restrict__ x,        // (M, DIM, 2)
    const float* __restrict__ dtw_t,    // (4096, 128)
    const float* __restrict__ pgw_t,    // (2048, 128)
    const float* __restrict__ Br,       // (2048, 128)
    const float* __restrict__ Bi,       // (2048, 128)
    const float* __restrict__ log_A_real,
    const float* __restrict__ log_A_imag,
    const float* __restrict__ dt_b,
    const float* __restrict__ dt_bias,
    const float* __restrict__ pg_b,
    float* __restrict__ Abuf,
    float* __restrict__ Bxbuf)
{
    const int s     = threadIdx.x & 127;   // 0..127 (wave-contiguous)
    const int g     = threadIdx.x >> 7;    // 0/1 row-half
    const int rbase = g * 16;
    const int m0    = blockIdx.x * 32;

    __shared__ __align__(16) float2 xs[32][64];   // 16 KB  (xr, xi)
    __shared__ __align__(16) float  cs[32][64];   // 8 KB   |x|

    float accd[16], accp[16], accbr[16], accbi[16];
    #pragma unroll
    for (int r = 0; r < 16; ++r) { accd[r]=0.f; accp[r]=0.f; accbr[r]=0.f; accbi[r]=0.f; }

    const float2* x2 = (const float2*)x;

    for (int kt = 0; kt < DIMC; kt += 64) {
        __syncthreads();
        #pragma unroll
        for (int j = 0; j < 8; ++j) {
            int i  = threadIdx.x + j * 256;
            int r  = i >> 6, kk = i & 63;
            float2 xv = x2[(size_t)(m0 + r) * DIMC + kt + kk];
            xs[r][kk] = xv;
            cs[r][kk] = sqrtf(fmaf(xv.x, xv.x, xv.y * xv.y));
        }
        __syncthreads();

        const float* wdr_p = dtw_t + (size_t)kt * SC + s;
        const float* wdi_p = dtw_t + (size_t)(DIMC + kt) * SC + s;
        const float* wbr_p = Br    + (size_t)kt * SC + s;
        const float* wbi_p = Bi    + (size_t)kt * SC + s;
        const float* wpg_p = pgw_t + (size_t)kt * SC + s;

        for (int kk = 0; kk < 64; kk += 2) {
            float w0dr = wdr_p[(size_t)kk*SC],     w1dr = wdr_p[(size_t)(kk+1)*SC];
            float w0di = wdi_p[(size_t)kk*SC],     w1di = wdi_p[(size_t)(kk+1)*SC];
            float w0br = wbr_p[(size_t)kk*SC],     w1br = wbr_p[(size_t)(kk+1)*SC];
            float w0bi = wbi_p[(size_t)kk*SC],     w1bi = wbi_p[(size_t)(kk+1)*SC];
            float w0pg = wpg_p[(size_t)kk*SC],     w1pg = wpg_p[(size_t)(kk+1)*SC];
            #pragma unroll
            for (int r2 = 0; r2 < 16; ++r2) {
                const int r = rbase + r2;
                float4 xv = *(const float4*)&xs[r][kk];   // (xr0,xi0,xr1,xi1)
                float2 cb = *(const float2*)&cs[r][kk];
                accd[r2]  = fmaf(xv.x,  w0dr, accd[r2]);
                accd[r2]  = fmaf(xv.y,  w0di, accd[r2]);
                accbr[r2] = fmaf(xv.x,  w0br, accbr[r2]);
                accbr[r2] = fmaf(-xv.y, w0bi, accbr[r2]);
                accbi[r2] = fmaf(xv.x,  w0bi, accbi[r2]);
                accbi[r2] = fmaf(xv.y,  w0br, accbi[r2]);
                accp[r2]  = fmaf(cb.x,  w0pg, accp[r2]);
                accd[r2]  = fmaf(xv.z,  w1dr, accd[r2]);
                accd[r2]  = fmaf(xv.w,  w1di, accd[r2]);
                accbr[r2] = fmaf(xv.z,  w1br, accbr[r2]);
                accbr[r2] = fmaf(-xv.w, w1bi, accbr[r2]);
                accbi[r2] = fmaf(xv.z,  w1bi, accbi[r2]);
                accbi[r2] = fmaf(xv.w,  w1br, accbi[r2]);
                accp[r2]  = fmaf(cb.y,  w1pg, accp[r2]);
            }
        }
    }

    // epilogue: dt=softplus, A = p + (1-p)*exp(-dt*eA)*eig, Bx = (1-p)*dt*Bx0
    float eAr   = expf(log_A_real[s]);
    float eig_r = cosf(log_A_imag[s]);
    float eig_i = sinf(log_A_imag[s]);
    float bsum  = dt_b[s] + dt_bias[s];
    float pgb   = pg_b[s];
    float2* A2  = (float2*)Abuf;
    float2* Bx2 = (float2*)Bxbuf;
    #pragma unroll 4
    for (int r2 = 0; r2 < 16; ++r2) {
        float z    = accd[r2] + bsum;
        float dt   = fmaxf(z, 0.f) + log1pf(expf(-fabsf(z)));   // softplus
        float amag = expf(-dt * eAr);
        float zp   = accp[r2] + pgb;
        float pr   = 1.f / (1.f + expf(-zp));
        float omp  = 1.f - pr;
        float Ar_  = fmaf(omp, amag * eig_r, pr);
        float Ai_  = omp * amag * eig_i;
        float sc   = omp * dt;
        size_t base = (size_t)(m0 + rbase + r2) * SC + s;
        A2[base]  = make_float2(Ar_, Ai_);
        Bx2[base] = make_float2(sc * accbr[r2], sc * accbi[r2]);
    }
}

// ---------------------------------------------------------------------------
// Kernel 2a: per-chunk reduce of (A,B) pairs. Grid = B*NC, block = 128 (s).
// ---------------------------------------------------------------------------
__global__ void scan_reduce(const float* __restrict__ Abuf,
                            const float* __restrict__ Bxbuf,
                            float* __restrict__ aggA,
                            float* __restrict__ aggB) {
    int s = threadIdx.x;
    int c = blockIdx.x & (NC-1);
    int b = blockIdx.x >> 6;
    const float2* A2  = (const float2*)Abuf;
    const float2* Bx2 = (const float2*)Bxbuf;
    size_t base = ((size_t)(b * LL + c * LCH) * SC + s);
    float2 a0 = A2[base], b0 = Bx2[base];
    float ar = a0.x, ai = a0.y, br = b0.x, bi = b0.y;
    #pragma unroll 4
    for (int l = 1; l < LCH; ++l) {
        float2 al = A2[base + (size_t)l * SC];
        float2 bl = Bx2[base + (size_t)l * SC];
        float nar = ar*al.x - ai*al.y;
        float nai = ar*al.y + ai*al.x;
        float nbr = br*al.x - bi*al.y + bl.x;
        float nbi = br*al.y + bi*al.x + bl.y;
        ar = nar; ai = nai; br = nbr; bi = nbi;
    }
    ((float2*)aggA)[(size_t)blockIdx.x * SC + s] = make_float2(ar, ai);
    ((float2*)aggB)[(size_t)blockIdx.x * SC + s] = make_float2(br, bi);
}

// ---------------------------------------------------------------------------
// Kernel 2b: exclusive scan of chunk aggregates (spine). 512 threads total.
// ---------------------------------------------------------------------------
__global__ void scan_spine(const float* __restrict__ aggA,
                           const float* __restrict__ aggB,
                           float* __restrict__ preB) {
    int t = threadIdx.x + blockIdx.x * blockDim.x;   // 0..511
    int s = t & 127, b = t >> 7;
    const float2* A2 = (const float2*)aggA;
    const float2* B2 = (const float2*)aggB;
    float2* P2 = (float2*)preB;
    float pa_r = 1.f, pa_i = 0.f, pb_r = 0.f, pb_i = 0.f;
    for (int c = 0; c < NC; ++c) {
        size_t idx = (size_t)(b * NC + c) * SC + s;
        P2[idx] = make_float2(pb_r, pb_i);
        float2 a = A2[idx], bb = B2[idx];
        float nar = pa_r*a.x - pa_i*a.y;
        float nai = pa_r*a.y + pa_i*a.x;
        float nbr = pb_r*a.x - pb_i*a.y + bb.x;
        float nbi = pb_r*a.y + pb_i*a.x + bb.y;
        pa_r = nar; pa_i = nai; pb_r = nbr; pb_i = nbi;
    }
}

// ---------------------------------------------------------------------------
// Kernel 2c: apply prefixes, write h (and h_last output). Grid = B*NC.
// ---------------------------------------------------------------------------
__global__ void scan_apply(const float* __restrict__ Abuf,
                           const float* __restrict__ Bxbuf,
                           const float* __restrict__ preB,
                           float* __restrict__ hbuf,
                           float* __restrict__ d_out) {
    int s = threadIdx.x;
    int c = blockIdx.x & (NC-1);
    int b = blockIdx.x >> 6;
    const float2* A2  = (const float2*)Abuf;
    const float2* Bx2 = (const float2*)Bxbuf;
    float2 hp = ((const float2*)preB)[(size_t)blockIdx.x * SC + s];
    float hr = hp.x, hi = hp.y;
    size_t base = ((size_t)(b * LL + c * LCH) * SC + s);
    float2* h2 = (float2*)hbuf;
    #pragma unroll 4
    for (int l = 0; l < LCH; ++l) {
        float2 al = A2[base + (size_t)l * SC];
        float2 bl = Bx2[base + (size_t)l * SC];
        float nr = al.x*hr - al.y*hi + bl.x;
        float ni = al.x*hi + al.y*hr + bl.y;
        hr = nr; hi = ni;
        h2[base + (size_t)l * SC] = make_float2(hr, hi);
    }
    if (c == NC - 1) {   // l = L-1 -> h_last
        float2* hl = (float2*)(d_out + (size_t)MM * DIMC * 2);
        hl[b * SC + s] = make_float2(hr, hi);
    }
}

// ---------------------------------------------------------------------------
// Kernel 3: y = h @ (Cr + i Ci) + D*x. Block = 256 (d), 32 rows/block.
// s processed in pairs -> ds_read_b128 (8 FMAs per LDS instr).
// ---------------------------------------------------------------------------
__global__ __launch_bounds__(256, 2) void phase3(
    const float* __restrict__ hbuf,
    const float* __restrict__ Cr,      // (S, DIM)
    const float* __restrict__ Ci,      // (S, DIM)
    const float* __restrict__ x,       // (M, DIM, 2)
    const float* __restrict__ Dw,      // (DIM, 2)
    float* __restrict__ out)
{
    const int tid = threadIdx.x;
    const int m0  = blockIdx.x * 32;
    __shared__ __align__(16) float2 hs[32][128];   // 32 KB
    const float2* h2 = (const float2*)hbuf;
    #pragma unroll
    for (int j = 0; j < 16; ++j) {
        int i = tid + j * 256;
        hs[i >> 7][i & 127] = h2[(size_t)(m0 + (i >> 7)) * SC + (i & 127)];
    }
    __syncthreads();

    const float2* x2 = (const float2*)x;
    float2* o2 = (float2*)out;

    for (int d0 = 0; d0 < DIMC; d0 += 256) {
        int d = d0 + tid;
        float yr[32], yi[32];
        #pragma unroll
        for (int r = 0; r < 32; ++r) { yr[r] = 0.f; yi[r] = 0.f; }
        for (int s = 0; s < SC; s += 2) {
            float cr0 = Cr[(size_t)s * DIMC + d];
            float ci0 = Ci[(size_t)s * DIMC + d];
            float cr1 = Cr[(size_t)(s+1) * DIMC + d];
            float ci1 = Ci[(size_t)(s+1) * DIMC + d];
            #pragma unroll
            for (int r = 0; r < 32; ++r) {
                float4 h = *(const float4*)&hs[r][s];   // (hr0,hi0,hr1,hi1)
                yr[r] = fmaf(h.x,  cr0, yr[r]);
                yr[r] = fmaf(-h.y, ci0, yr[r]);
                yi[r] = fmaf(h.x,  ci0, yi[r]);
                yi[r] = fmaf(h.y,  cr0, yi[r]);
                yr[r] = fmaf(h.z,  cr1, yr[r]);
                yr[r] = fmaf(-h.w, ci1, yr[r]);
                yi[r] = fmaf(h.z,  ci1, yi[r]);
                yi[r] = fmaf(h.w,  cr1, yi[r]);
            }
        }
        float dre = Dw[d*2], dim_ = Dw[d*2 + 1];
        #pragma unroll 4
        for (int r = 0; r < 32; ++r) {
            size_t m = (size_t)(m0 + r);
            float2 xv = x2[m * DIMC + d];
            float orr = yr[r] + dre * xv.x - dim_ * xv.y;
            float oii = yi[r] + dre * xv.y + dim_ * xv.x;
            o2[m * DIMC + d] = make_float2(orr, oii);
        }
    }
}

// ---------------------------------------------------------------------------
extern "C" void kernel_launch(void* const* d_in, const int* in_sizes, int n_in,
                              void* d_out, int out_size, void* d_ws, size_t ws_size,
                              hipStream_t stream) {
    const float* x          = (const float*)d_in[0];
    const float* log_A_real = (const float*)d_in[1];
    const float* log_A_imag = (const float*)d_in[2];
    const float* Dw         = (const float*)d_in[3];
    const float* dt_w       = (const float*)d_in[4];
    const float* dt_b       = (const float*)d_in[5];
    const float* dt_bias    = (const float*)d_in[6];
    const float* Br         = (const float*)d_in[7];
    const float* Bi         = (const float*)d_in[8];
    const float* Cr         = (const float*)d_in[9];
    const float* Ci         = (const float*)d_in[10];
    const float* pg_w       = (const float*)d_in[11];
    const float* pg_b       = (const float*)d_in[12];

    float* out = (float*)d_out;
    float* ws  = (float*)d_ws;

    float* dtw_t = ws;                        // 524288
    float* pgw_t = dtw_t + 2*DIMC*SC;         // 262144
    float* Abuf  = pgw_t + DIMC*SC;           // 4194304 (M*S complex)
    float* Bxbuf = Abuf  + (size_t)MM*SC*2;   // 4194304
    float* hbuf  = Bxbuf + (size_t)MM*SC*2;   // 4194304
    float* aggA  = hbuf  + (size_t)MM*SC*2;   // 65536
    float* aggB  = aggA  + BB*NC*SC*2;        // 65536
    float* preB  = aggB  + BB*NC*SC*2;        // 65536

    hipLaunchKernelGGL(transpose_w, dim3(3072), dim3(256), 0, stream,
                       dt_w, pg_w, dtw_t, pgw_t);
    hipLaunchKernelGGL(phase1, dim3(MM/32), dim3(256), 0, stream,
                       x, dtw_t, pgw_t, Br, Bi, log_A_real, log_A_imag,
                       dt_b, dt_bias, pg_b, Abuf, Bxbuf);
    hipLaunchKernelGGL(scan_reduce, dim3(BB*NC), dim3(128), 0, stream,
                       Abuf, Bxbuf, aggA, aggB);
    hipLaunchKernelGGL(scan_spine, dim3(2), dim3(256), 0, stream,
                       aggA, aggB, preB);
    hipLaunchKernelGGL(scan_apply, dim3(BB*NC), dim3(128), 0, stream,
                       Abuf, Bxbuf, preB, hbuf, out);
    hipLaunchKernelGGL(phase3, dim3(MM/32), dim3(256), 0, stream,
                       hbuf, Cr, Ci, x, Dw, out);
}